// Round 2
// baseline (1651.704 us; speedup 1.0000x reference)
//
#include <hip/hip_runtime.h>

#define T_ 32
#define DM 64
#define DI 128
#define NLAYER 4

#define XE_LD 68
#define XC_LD 132
#define DBL_LD 40

__global__ __launch_bounds__(256, 2) void mamba_polar_kernel(
    const float* __restrict__ ch, const float* __restrict__ snr,
    const int*   __restrict__ froz, const float* __restrict__ emb,
    const float* __restrict__ l1w, const float* __restrict__ l1b,
    const float* __restrict__ l2w, const float* __restrict__ l2b,
    const float* __restrict__ inw, const float* __restrict__ inb,
    const float* __restrict__ blnw, const float* __restrict__ blnb,
    const float* __restrict__ ipw, const float* __restrict__ cvw,
    const float* __restrict__ cvb, const float* __restrict__ xpw,
    const float* __restrict__ dtw, const float* __restrict__ dtbp,
    const float* __restrict__ alog, const float* __restrict__ dpar,
    const float* __restrict__ opw, const float* __restrict__ plnw,
    const float* __restrict__ plnb, const float* __restrict__ fw,
    const float* __restrict__ fb, float* __restrict__ out)
{
    __shared__ float s_xe[T_][XE_LD];   // residual stream
    __shared__ float s_h[T_][DM];       // LN output
    __shared__ float s_xc[T_][XC_LD];   // x-branch
    __shared__ float s_z[T_][XC_LD];    // z, later gated y
    __shared__ float s_dbl[T_][DBL_LD]; // dt_rank(4) + B(16) + C(16)

    const int tid = threadIdx.x;
    const int b = blockIdx.x;

    // ---------------- P0: embedding + input projection ----------------
    // mapping: c = tid&63 (column), rb = tid>>6, rows r = rb*8+rr
    const int c0 = tid & 63;
    const int rb = tid >> 6;
    float x0r[8];
    {
        float chv[8]; int pv[8];
        #pragma unroll
        for (int rr = 0; rr < 8; ++rr) {
            int r = rb * 8 + rr;
            chv[rr] = ch[b * T_ + r];
            pv[rr] = froz[b * T_ + r];
        }
        float sv = snr[b];
        float W1dot = 0.f, B1dot = 0.f, SEdot = 0.f, D0dot = 0.f, D1dot = 0.f;
        const float4* iwr = reinterpret_cast<const float4*>(inw + c0 * 192);
        #pragma unroll
        for (int k4 = 0; k4 < 16; ++k4) {
            float4 w1 = reinterpret_cast<const float4*>(l1w)[k4];
            float4 b1 = reinterpret_cast<const float4*>(l1b)[k4];
            float4 iw = iwr[k4];
            W1dot += w1.x*iw.x + w1.y*iw.y + w1.z*iw.z + w1.w*iw.w;
            B1dot += b1.x*iw.x + b1.y*iw.y + b1.z*iw.z + b1.w*iw.w;
            float4 w2 = reinterpret_cast<const float4*>(l2w)[k4];
            float4 b2 = reinterpret_cast<const float4*>(l2b)[k4];
            float4 iw2 = iwr[16 + k4];
            SEdot += (sv*w2.x + b2.x)*iw2.x + (sv*w2.y + b2.y)*iw2.y
                   + (sv*w2.z + b2.z)*iw2.z + (sv*w2.w + b2.w)*iw2.w;
            float4 e0 = reinterpret_cast<const float4*>(emb)[k4];
            float4 e1 = reinterpret_cast<const float4*>(emb + 64)[k4];
            float4 iw3 = iwr[32 + k4];
            D0dot += e0.x*iw3.x + e0.y*iw3.y + e0.z*iw3.z + e0.w*iw3.w;
            D1dot += e1.x*iw3.x + e1.y*iw3.y + e1.z*iw3.z + e1.w*iw3.w;
        }
        float base = inb[c0] + B1dot + SEdot;
        #pragma unroll
        for (int rr = 0; rr < 8; ++rr) {
            float v = base + chv[rr] * W1dot + (pv[rr] ? D1dot : D0dot);
            s_xe[rb * 8 + rr][c0] = v;
            x0r[rr] = v;
        }
    }
    __syncthreads();

    // ---------------- layers ----------------
    for (int l = 0; l < NLAYER; ++l) {
        // ---- LayerNorm: xe -> h ----
        {
            int r = tid >> 3, j = tid & 7;
            float4 v0 = *reinterpret_cast<const float4*>(&s_xe[r][j * 8]);
            float4 v1 = *reinterpret_cast<const float4*>(&s_xe[r][j * 8 + 4]);
            float s = v0.x + v0.y + v0.z + v0.w + v1.x + v1.y + v1.z + v1.w;
            float s2 = v0.x*v0.x + v0.y*v0.y + v0.z*v0.z + v0.w*v0.w
                     + v1.x*v1.x + v1.y*v1.y + v1.z*v1.z + v1.w*v1.w;
            #pragma unroll
            for (int m = 1; m < 8; m <<= 1) {
                s  += __shfl_xor(s, m, 8);
                s2 += __shfl_xor(s2, m, 8);
            }
            float mean = s * (1.f / 64.f);
            float var = s2 * (1.f / 64.f) - mean * mean;
            float rstd = rsqrtf(var + 1e-5f);
            float4 wv0 = *reinterpret_cast<const float4*>(blnw + l * 64 + j * 8);
            float4 wv1 = *reinterpret_cast<const float4*>(blnw + l * 64 + j * 8 + 4);
            float4 bv0 = *reinterpret_cast<const float4*>(blnb + l * 64 + j * 8);
            float4 bv1 = *reinterpret_cast<const float4*>(blnb + l * 64 + j * 8 + 4);
            float4 o0, o1;
            o0.x = (v0.x - mean) * rstd * wv0.x + bv0.x;
            o0.y = (v0.y - mean) * rstd * wv0.y + bv0.y;
            o0.z = (v0.z - mean) * rstd * wv0.z + bv0.z;
            o0.w = (v0.w - mean) * rstd * wv0.w + bv0.w;
            o1.x = (v1.x - mean) * rstd * wv1.x + bv1.x;
            o1.y = (v1.y - mean) * rstd * wv1.y + bv1.y;
            o1.z = (v1.z - mean) * rstd * wv1.z + bv1.z;
            o1.w = (v1.w - mean) * rstd * wv1.w + bv1.w;
            *reinterpret_cast<float4*>(&s_h[r][j * 8]) = o0;
            *reinterpret_cast<float4*>(&s_h[r][j * 8 + 4]) = o1;
        }
        __syncthreads();

        for (int dd = 0; dd < 2; ++dd) {
            const int off2 = l * 2 + dd;

            // ---- in_proj: h -> xc, z  (256x64 weight, tiles 4t x 8i) ----
            {
                int ib = tid & 31, tb = tid >> 5;
                float acc[4][8];
                #pragma unroll
                for (int tt = 0; tt < 4; ++tt)
                    #pragma unroll
                    for (int ii = 0; ii < 8; ++ii) acc[tt][ii] = 0.f;
                const float* ipb = ipw + (size_t)off2 * 256 * 64 + (size_t)(ib * 8) * 64;
                #pragma unroll 4
                for (int k4 = 0; k4 < 16; ++k4) {
                    float4 hv[4];
                    #pragma unroll
                    for (int tt = 0; tt < 4; ++tt) {
                        int t = tb * 4 + tt;
                        int tr = dd ? (31 - t) : t;
                        hv[tt] = *reinterpret_cast<const float4*>(&s_h[tr][k4 * 4]);
                    }
                    #pragma unroll
                    for (int ii = 0; ii < 8; ++ii) {
                        float4 wv = *reinterpret_cast<const float4*>(ipb + ii * 64 + k4 * 4);
                        #pragma unroll
                        for (int tt = 0; tt < 4; ++tt)
                            acc[tt][ii] += hv[tt].x*wv.x + hv[tt].y*wv.y
                                         + hv[tt].z*wv.z + hv[tt].w*wv.w;
                    }
                }
                #pragma unroll
                for (int tt = 0; tt < 4; ++tt) {
                    int t = tb * 4 + tt;
                    float* dst = (ib < 16) ? &s_xc[t][ib * 8] : &s_z[t][(ib - 16) * 8];
                    float4 a0 = make_float4(acc[tt][0], acc[tt][1], acc[tt][2], acc[tt][3]);
                    float4 a1 = make_float4(acc[tt][4], acc[tt][5], acc[tt][6], acc[tt][7]);
                    *reinterpret_cast<float4*>(dst) = a0;
                    *reinterpret_cast<float4*>(dst + 4) = a1;
                }
            }
            __syncthreads();

            // ---- causal depthwise conv(4) + SiLU, in place on xc ----
            {
                int d = tid & 127, hf = tid >> 7;
                int t0 = hf * 16;
                float xv[19];
                #pragma unroll
                for (int i = 0; i < 3; ++i)
                    xv[i] = (t0 - 3 + i >= 0) ? s_xc[t0 - 3 + i][d] : 0.f;
                #pragma unroll
                for (int i = 0; i < 16; ++i) xv[3 + i] = s_xc[t0 + i][d];
                float4 w = *reinterpret_cast<const float4*>(cvw + (size_t)off2 * 512 + d * 4);
                float bb = cvb[off2 * 128 + d];
                __syncthreads();
                #pragma unroll
                for (int i = 0; i < 16; ++i) {
                    float v = xv[i]*w.x + xv[i+1]*w.y + xv[i+2]*w.z + xv[i+3]*w.w + bb;
                    v = v / (1.f + __expf(-v));   // SiLU
                    s_xc[t0 + i][d] = v;
                }
            }
            __syncthreads();

            // ---- xproj: xc -> dbl (36 cols), tiles 4j x 2t on 144 threads ----
            if (tid < 144) {
                int jb = tid % 9, tb2 = tid / 9;  // j = jb*4.., t = tb2*2..
                float acc[2][4];
                #pragma unroll
                for (int tt = 0; tt < 2; ++tt)
                    #pragma unroll
                    for (int jj = 0; jj < 4; ++jj) acc[tt][jj] = 0.f;
                const float* xpb = xpw + (size_t)off2 * 36 * 128 + (size_t)(jb * 4) * 128;
                #pragma unroll 4
                for (int k4 = 0; k4 < 32; ++k4) {
                    float4 xv0 = *reinterpret_cast<const float4*>(&s_xc[tb2 * 2][k4 * 4]);
                    float4 xv1 = *reinterpret_cast<const float4*>(&s_xc[tb2 * 2 + 1][k4 * 4]);
                    #pragma unroll
                    for (int jj = 0; jj < 4; ++jj) {
                        float4 wv = *reinterpret_cast<const float4*>(xpb + jj * 128 + k4 * 4);
                        acc[0][jj] += xv0.x*wv.x + xv0.y*wv.y + xv0.z*wv.z + xv0.w*wv.w;
                        acc[1][jj] += xv1.x*wv.x + xv1.y*wv.y + xv1.z*wv.z + xv1.w*wv.w;
                    }
                }
                #pragma unroll
                for (int tt = 0; tt < 2; ++tt)
                    #pragma unroll
                    for (int jj = 0; jj < 4; ++jj)
                        s_dbl[tb2 * 2 + tt][jb * 4 + jj] = acc[tt][jj];
            }
            __syncthreads();

            // ---- selective scan + gating (threads < 128, thread owns channel d) ----
            if (tid < 128) {
                int d = tid;
                float A2[16];
                #pragma unroll
                for (int q = 0; q < 4; ++q) {
                    float4 a = *reinterpret_cast<const float4*>(
                        alog + ((size_t)off2 * 128 + d) * 16 + q * 4);
                    A2[q*4+0] = -__expf(a.x) * 1.44269504f;
                    A2[q*4+1] = -__expf(a.y) * 1.44269504f;
                    A2[q*4+2] = -__expf(a.z) * 1.44269504f;
                    A2[q*4+3] = -__expf(a.w) * 1.44269504f;
                }
                float4 dw = *reinterpret_cast<const float4*>(dtw + (size_t)off2 * 512 + d * 4);
                float dbv = dtbp[off2 * 128 + d];
                float Dv = dpar[off2 * 128 + d];
                float hst[16];
                #pragma unroll
                for (int s = 0; s < 16; ++s) hst[s] = 0.f;
                for (int t = 0; t < T_; ++t) {
                    float4 r4 = *reinterpret_cast<const float4*>(&s_dbl[t][0]);
                    float draw = dbv + r4.x*dw.x + r4.y*dw.y + r4.z*dw.z + r4.w*dw.w;
                    // softplus
                    float dtv = fmaxf(draw, 0.f) + log1pf(__expf(-fabsf(draw)));
                    float xv = s_xc[t][d];
                    float p = dtv * xv;
                    float Bf[16], Cf[16];
                    #pragma unroll
                    for (int q = 0; q < 4; ++q) {
                        *reinterpret_cast<float4*>(&Bf[q*4]) =
                            *reinterpret_cast<const float4*>(&s_dbl[t][4 + q*4]);
                        *reinterpret_cast<float4*>(&Cf[q*4]) =
                            *reinterpret_cast<const float4*>(&s_dbl[t][20 + q*4]);
                    }
                    float part = 0.f;
                    #pragma unroll
                    for (int s = 0; s < 16; ++s) {
                        float dA = exp2f(dtv * A2[s]);
                        hst[s] = dA * hst[s] + p * Bf[s];
                        part += hst[s] * Cf[s];
                    }
                    float zv = s_z[t][d];
                    float g = (part + Dv * xv) * (zv / (1.f + __expf(-zv)));
                    s_z[t][d] = g;   // gated y, in place
                }
            }
            __syncthreads();

            // ---- out_proj: y(=s_z) -> += xe  (64x128 weight, tiles 4m x 2t) ----
            {
                int mb = tid & 15, tb3 = tid >> 4;
                float acc[2][4];
                #pragma unroll
                for (int tt = 0; tt < 2; ++tt)
                    #pragma unroll
                    for (int mm = 0; mm < 4; ++mm) acc[tt][mm] = 0.f;
                const float* opb = opw + (size_t)off2 * 64 * 128 + (size_t)(mb * 4) * 128;
                #pragma unroll 4
                for (int d4 = 0; d4 < 32; ++d4) {
                    float4 y0 = *reinterpret_cast<const float4*>(&s_z[tb3 * 2][d4 * 4]);
                    float4 y1 = *reinterpret_cast<const float4*>(&s_z[tb3 * 2 + 1][d4 * 4]);
                    #pragma unroll
                    for (int mm = 0; mm < 4; ++mm) {
                        float4 wv = *reinterpret_cast<const float4*>(opb + mm * 128 + d4 * 4);
                        acc[0][mm] += y0.x*wv.x + y0.y*wv.y + y0.z*wv.z + y0.w*wv.w;
                        acc[1][mm] += y1.x*wv.x + y1.y*wv.y + y1.z*wv.z + y1.w*wv.w;
                    }
                }
                #pragma unroll
                for (int tt = 0; tt < 2; ++tt) {
                    int t = tb3 * 2 + tt;
                    int tr = dd ? (31 - t) : t;
                    #pragma unroll
                    for (int mm = 0; mm < 4; ++mm)
                        s_xe[tr][mb * 4 + mm] += acc[tt][mm];
                }
            }
            __syncthreads();
        } // dd
    } // l

    // ---------------- final: residual + LN + linear head ----------------
    {
        float pw = plnw[c0], pb = plnb[c0], fwc = fw[c0];
        float fbv = fb[0];
        #pragma unroll
        for (int rr = 0; rr < 8; ++rr) {
            int r = rb * 8 + rr;
            float v = s_xe[r][c0] + x0r[rr];   // RESIDUAL_SCALE = 1
            float s = v, s2 = v * v;
            #pragma unroll
            for (int m = 1; m < 64; m <<= 1) {
                s  += __shfl_xor(s, m, 64);
                s2 += __shfl_xor(s2, m, 64);
            }
            float mean = s * (1.f / 64.f);
            float var = s2 * (1.f / 64.f) - mean * mean;
            float n = (v - mean) * rsqrtf(var + 1e-5f) * pw + pb;
            float contrib = n * fwc;
            #pragma unroll
            for (int m = 1; m < 64; m <<= 1) contrib += __shfl_xor(contrib, m, 64);
            if (c0 == 0) out[b * T_ + r] = contrib + fbv;
        }
    }
}

extern "C" void kernel_launch(void* const* d_in, const int* in_sizes, int n_in,
                              void* d_out, int out_size, void* d_ws, size_t ws_size,
                              hipStream_t stream) {
    mamba_polar_kernel<<<1024, 256, 0, stream>>>(
        (const float*)d_in[0],  (const float*)d_in[1],  (const int*)d_in[2],
        (const float*)d_in[3],  (const float*)d_in[4],  (const float*)d_in[5],
        (const float*)d_in[6],  (const float*)d_in[7],  (const float*)d_in[8],
        (const float*)d_in[9],  (const float*)d_in[10], (const float*)d_in[11],
        (const float*)d_in[12], (const float*)d_in[13], (const float*)d_in[14],
        (const float*)d_in[15], (const float*)d_in[16], (const float*)d_in[17],
        (const float*)d_in[18], (const float*)d_in[19], (const float*)d_in[20],
        (const float*)d_in[21], (const float*)d_in[22], (const float*)d_in[23],
        (const float*)d_in[24], (float*)d_out);
}